// Round 9
// baseline (229.935 us; speedup 1.0000x reference)
//
#include <hip/hip_runtime.h>

typedef __attribute__((ext_vector_type(8))) short s8bf;     // 8 bf16 payload
typedef __attribute__((ext_vector_type(8))) __bf16 v8bf;    // MFMA operand type
typedef __attribute__((ext_vector_type(4))) float f32x4;
typedef __attribute__((ext_vector_type(16))) float f32x16;

__device__ __forceinline__ short f2bf(float f) {
  union { float f; unsigned u; } v; v.f = f;
  unsigned r = v.u + 0x7FFFu + ((v.u >> 16) & 1u);  // RNE
  return (short)(r >> 16);
}

__device__ __forceinline__ f32x4 mfma16(s8bf a, s8bf b, f32x4 c) {
  return __builtin_amdgcn_mfma_f32_16x16x32_bf16(
      __builtin_bit_cast(v8bf, a), __builtin_bit_cast(v8bf, b), c, 0, 0, 0);
}

__device__ __forceinline__ f32x16 mfma32(s8bf a, s8bf b, f32x16 c) {
  return __builtin_amdgcn_mfma_f32_32x32x16_bf16(
      __builtin_bit_cast(v8bf, a), __builtin_bit_cast(v8bf, b), c, 0, 0, 0);
}

__device__ __forceinline__ void gl_lds16(const void* g, void* l) {
  __builtin_amdgcn_global_load_lds(
      (const __attribute__((address_space(1))) unsigned*)g,
      (__attribute__((address_space(3))) unsigned*)l, 16, 0, 0);
}

// ---------------- f32 -> bf16 cast (vectorized) ----------------
__global__ void cvt_f32_bf16_k(const float* __restrict__ in, short* __restrict__ out, int n4) {
  int i = blockIdx.x * 256 + threadIdx.x;
  if (i < n4) {
    float4 v = ((const float4*)in)[i];
    short4 o;
    o.x = f2bf(v.x); o.y = f2bf(v.y); o.z = f2bf(v.z); o.w = f2bf(v.w);
    ((short4*)out)[i] = o;
  }
}

// ---------------- W [K][N] f32 -> Wt [N][K] bf16 ----------------
__global__ void transp_bf16_k(const float* __restrict__ W, short* __restrict__ Wt, int K, int N) {
  __shared__ float t[32][33];
  int k0 = blockIdx.x * 32, n0 = blockIdx.y * 32;
  int tx = threadIdx.x & 31, ty = threadIdx.x >> 5;  // ty 0..7
  #pragma unroll
  for (int i = 0; i < 4; ++i)
    t[ty + i * 8][tx] = W[(size_t)(k0 + ty + i * 8) * N + n0 + tx];
  __syncthreads();
  #pragma unroll
  for (int i = 0; i < 4; ++i)
    Wt[(size_t)(n0 + ty + i * 8) * K + k0 + tx] = f2bf(t[tx][ty + i * 8]);
}

// ---------------- mask -> additive bias, dtype-robust ----------------
__global__ void mask_bias_k(const void* __restrict__ mask, float* __restrict__ bias, int n) {
  __shared__ int fmt;  // 0=u8, 1=i32, 2=f32
  const unsigned char* p8 = (const unsigned char*)mask;
  if (threadIdx.x == 0) {
    const float* pf = (const float*)mask;
    int allf = 1, anyone = 0;
    for (int i = 0; i < 64; ++i) {
      float f = pf[i];
      if (f != 0.0f && f != 1.0f) allf = 0;
      if (f == 1.0f) anyone = 1;
    }
    int any13 = 0;
    for (int i = 0; i < 256; ++i) if ((i & 3) && p8[i]) any13 = 1;
    fmt = (allf && anyone) ? 2 : (any13 ? 0 : 1);
  }
  __syncthreads();
  int j = threadIdx.x;
  if (j < n) {
    int m;
    if (fmt == 2)      m = (((const float*)mask)[j] != 0.0f);
    else if (fmt == 0) m = (p8[j] != 0);
    else               m = (((const int*)mask)[j] != 0);
    bias[j] = m ? 0.0f : -1e30f;
  }
}

// ======== 32x32-MFMA ks-pipelined GEMM, p-split LDS layout (0-conflict family) ========
// A[M][K] bf16 @ Bt[N][K]^T -> C[M][N].  MODE 0: bf16 store, 1: f32 store.
// BM=BN=256, BK=64, 8 waves (2x4), wave tile 128x64, 128KB dynamic LDS (2 x 64KB).
// Buffer layout: 8 sub-subtiles of 8KB, indexed by ks=(kh,p): A@ks*8192, B@32768+ks*8192.
// Sub-subtile = 256 rows x 16 elems(32B); line L(0..63) = rows {4L..4L+3} x 2 chunks.
// Logical slot = 2*(row&3) + chunk;  phys slot = logical ^ (line&7)  [r6 family: each
// wave b128 read covers 8 lines x all 8 slots -> measured-zero-conflict pattern].
// Stage = linear dest + inverse-swizzled source (rule #21); 8 x 8KB instrs per tile.
// Pipeline per tile (2 barriers): pre-read ks0; {read ks+1, MFMA ks} x4 (compiler
// auto-lgkmcnt overlaps drain with MFMA); bar; stage(t+2)->cur; vmcnt(8); bar.
template<int MODE>
__global__ __launch_bounds__(512, 2) void gemm32_k(
    const short* __restrict__ A, const short* __restrict__ Bt, void* __restrict__ C,
    int M, int N, int K)
{
  extern __shared__ char ldsb[];
  const int tid = threadIdx.x, wid = tid >> 6, lane = tid & 63;
  const int nbx = N / 256;
  const int nwg = gridDim.x, bid = blockIdx.x;
  const int swz = (bid & 7) * (nwg >> 3) + (bid >> 3);   // nwg % 8 == 0
  const int m0 = (swz / nbx) * 256, n0 = (swz % nbx) * 256;
  const int wm = wid >> 2, wn = wid & 3;
  const int NT = K / 64;

  // ---- ds_read offsets within a sub-subtile (ks base added at use site)
  const int lr = lane & 31;                 // fragment row (A) / col (B)
  const int hk = lane >> 5;                 // 16B chunk within 32B
  int aoff[4], boff[2];
  #pragma unroll
  for (int mf = 0; mf < 4; ++mf) {
    int line = wm * 32 + mf * 8 + (lr >> 2);
    int slot = (2 * (lr & 3) + hk) ^ (line & 7);
    aoff[mf] = line * 128 + slot * 16;
  }
  #pragma unroll
  for (int nf = 0; nf < 2; ++nf) {
    int line = wn * 16 + nf * 8 + (lr >> 2);
    int slot = (2 * (lr & 3) + hk) ^ (line & 7);
    boff[nf] = 32768 + line * 128 + slot * 16;
  }

  // ---- stage sources: thread t -> line t>>3, phys slot t&7, logical ls ->
  // row 4*(t>>3)+(ls>>1), chunk (ls&1). Global k = ktile*64 + ks*16 + (ls&1)*8.
  const int ls = (tid & 7) ^ ((tid >> 3) & 7);
  const int srow4 = 4 * (tid >> 3) + (ls >> 1);
  const int scol = (ls & 1) * 8;
  const short* srcA = A  + (size_t)(m0 + srow4) * K + scol;
  const short* srcB = Bt + (size_t)(n0 + srow4) * K + scol;
  const int d16 = tid * 16;

  auto stage = [&](int koff, int bo_) {
    gl_lds16(srcA + koff,      ldsb + bo_ + 0     + d16);   // kh0 p0
    gl_lds16(srcA + koff + 16, ldsb + bo_ + 8192  + d16);   // kh0 p1
    gl_lds16(srcA + koff + 32, ldsb + bo_ + 16384 + d16);   // kh1 p0
    gl_lds16(srcA + koff + 48, ldsb + bo_ + 24576 + d16);   // kh1 p1
    gl_lds16(srcB + koff,      ldsb + bo_ + 32768 + d16);
    gl_lds16(srcB + koff + 16, ldsb + bo_ + 40960 + d16);
    gl_lds16(srcB + koff + 32, ldsb + bo_ + 49152 + d16);
    gl_lds16(srcB + koff + 48, ldsb + bo_ + 57344 + d16);
  };

  f32x16 acc[4][2] = {};
  s8bf a0[4], a1[4], b0[2], b1[2];

  // ---- prologue: S(0)->buf0, S(1)->buf1; vmcnt(8) drains S(0)
  stage(0, 0);
  stage(((1 < NT) ? 1 : 0) * 64, 65536);
  asm volatile("s_waitcnt vmcnt(8)" ::: "memory");
  __builtin_amdgcn_s_barrier();

  for (int t = 0; t < NT; ++t) {
    const int bo = (t & 1) * 65536;
    const int kt2 = ((t + 2) < NT ? (t + 2) : (NT - 1)) * 64;
    // pre-read ks0
    #pragma unroll
    for (int mf = 0; mf < 4; ++mf) a0[mf] = *(const s8bf*)(ldsb + bo + aoff[mf]);
    #pragma unroll
    for (int nf = 0; nf < 2; ++nf) b0[nf] = *(const s8bf*)(ldsb + bo + boff[nf]);
    // ks0: read ks1, MFMA set0
    #pragma unroll
    for (int mf = 0; mf < 4; ++mf) a1[mf] = *(const s8bf*)(ldsb + bo + 8192 + aoff[mf]);
    #pragma unroll
    for (int nf = 0; nf < 2; ++nf) b1[nf] = *(const s8bf*)(ldsb + bo + 8192 + boff[nf]);
    __builtin_amdgcn_s_setprio(1);
    #pragma unroll
    for (int mf = 0; mf < 4; ++mf)
      #pragma unroll
      for (int nf = 0; nf < 2; ++nf)
        acc[mf][nf] = mfma32(a0[mf], b0[nf], acc[mf][nf]);
    __builtin_amdgcn_s_setprio(0);
    // ks1: read ks2, MFMA set1
    #pragma unroll
    for (int mf = 0; mf < 4; ++mf) a0[mf] = *(const s8bf*)(ldsb + bo + 16384 + aoff[mf]);
    #pragma unroll
    for (int nf = 0; nf < 2; ++nf) b0[nf] = *(const s8bf*)(ldsb + bo + 16384 + boff[nf]);
    __builtin_amdgcn_s_setprio(1);
    #pragma unroll
    for (int mf = 0; mf < 4; ++mf)
      #pragma unroll
      for (int nf = 0; nf < 2; ++nf)
        acc[mf][nf] = mfma32(a1[mf], b1[nf], acc[mf][nf]);
    __builtin_amdgcn_s_setprio(0);
    // ks2: read ks3, MFMA set0
    #pragma unroll
    for (int mf = 0; mf < 4; ++mf) a1[mf] = *(const s8bf*)(ldsb + bo + 24576 + aoff[mf]);
    #pragma unroll
    for (int nf = 0; nf < 2; ++nf) b1[nf] = *(const s8bf*)(ldsb + bo + 24576 + boff[nf]);
    __builtin_amdgcn_s_setprio(1);
    #pragma unroll
    for (int mf = 0; mf < 4; ++mf)
      #pragma unroll
      for (int nf = 0; nf < 2; ++nf)
        acc[mf][nf] = mfma32(a0[mf], b0[nf], acc[mf][nf]);
    __builtin_amdgcn_s_setprio(0);
    // ks3: MFMA set1
    __builtin_amdgcn_s_setprio(1);
    #pragma unroll
    for (int mf = 0; mf < 4; ++mf)
      #pragma unroll
      for (int nf = 0; nf < 2; ++nf)
        acc[mf][nf] = mfma32(a1[mf], b1[nf], acc[mf][nf]);
    __builtin_amdgcn_s_setprio(0);
    // tile boundary: all waves done reading cur -> stage t+2 into cur
    __builtin_amdgcn_s_barrier();
    stage(kt2, bo);
    asm volatile("s_waitcnt vmcnt(8)" ::: "memory");   // S(t+1) landed; S(t+2) in flight
    __builtin_amdgcn_s_barrier();
  }
  asm volatile("s_waitcnt vmcnt(0)" ::: "memory");     // drain tail dummies

  // C store: 32x32 C-layout col=lane&31, row=(r&3)+8*(r>>2)+4*(lane>>5)
  const int rb = m0 + wm * 128 + 4 * hk;
  const int cb = n0 + wn * 64 + lr;
  #pragma unroll
  for (int mf = 0; mf < 4; ++mf)
    #pragma unroll
    for (int nf = 0; nf < 2; ++nf)
      #pragma unroll
      for (int r = 0; r < 16; ++r) {
        int row = rb + mf * 32 + (r & 3) + 8 * (r >> 2);
        int col = cb + nf * 32;
        float val = acc[mf][nf][r];
        if (MODE == 0) ((short*)C)[(size_t)row * N + col] = f2bf(val);
        else           ((float*)C)[(size_t)row * N + col] = val;
      }
}

// ---------------- m97-style GEMM for split-K K/V projection ----------------
// MODE 5: per-slice f32 partial store (no atomics): C[z][row][col], slice stride 256*3072
template<int MODE>
__global__ __launch_bounds__(256, 2) void gemm_bt_k(
    const short* __restrict__ A, const short* __restrict__ Bt, void* __restrict__ C,
    int M, int N, int K, int kchunk)
{
  __shared__ short aT[128 * 32];
  __shared__ short bT[128 * 32];
  const int m0 = blockIdx.x * 128, n0 = blockIdx.y * 128;
  const int wid = threadIdx.x >> 6, lane = threadIdx.x & 63;
  const int wr = wid >> 1, wc = wid & 1;
  const int k_lo = blockIdx.z * kchunk, k_hi = k_lo + kchunk;
  f32x4 acc[4][4] = {};
  const int srow = wid * 32 + (lane >> 2);
  const int skoff = (lane & 3) * 8;
  const short* aG = A + (size_t)(m0 + srow) * K + skoff;
  const short* bG = Bt + (size_t)(n0 + srow) * K + skoff;
  char* aL = (char*)aT + wid * 2048;
  char* bL = (char*)bT + wid * 2048;
  const short* ap = aT + (wr * 64 + (lane & 15)) * 32 + (lane >> 4) * 8;
  const short* bp = bT + (wc * 64 + (lane & 15)) * 32 + (lane >> 4) * 8;
  for (int k0 = k_lo; k0 < k_hi; k0 += 32) {
    gl_lds16(aG + k0, aL);
    gl_lds16(aG + (size_t)16 * K + k0, aL + 1024);
    gl_lds16(bG + k0, bL);
    gl_lds16(bG + (size_t)16 * K + k0, bL + 1024);
    __syncthreads();
    s8bf af[4], bf[4];
    #pragma unroll
    for (int i = 0; i < 4; ++i) {
      af[i] = *(const s8bf*)(ap + i * 512);
      bf[i] = *(const s8bf*)(bp + i * 512);
    }
    #pragma unroll
    for (int mi = 0; mi < 4; ++mi)
      #pragma unroll
      for (int ni = 0; ni < 4; ++ni)
        acc[mi][ni] = mfma16(af[mi], bf[ni], acc[mi][ni]);
    __syncthreads();
  }
  const int r0 = m0 + wr * 64 + ((lane >> 4) << 2);
  const int c0 = n0 + wc * 64 + (lane & 15);
  float* Cf = (float*)C + (size_t)blockIdx.z * 786432;
  #pragma unroll
  for (int mi = 0; mi < 4; ++mi)
    #pragma unroll
    for (int ni = 0; ni < 4; ++ni)
      #pragma unroll
      for (int v = 0; v < 4; ++v) {
        int row = r0 + mi * 16 + v, col = c0 + ni * 16;
        Cf[(size_t)row * N + col] = acc[mi][ni][v];
      }
}

// ---------------- reduce 4 split-K slices -> bf16 K (row-major) + V^T ----------------
__global__ void kv_reduce_k(const float* __restrict__ part, short* __restrict__ kbf,
                            short* __restrict__ vtbf) {
  int t = blockIdx.x * 256 + threadIdx.x;          // t < 196608
  int row = t / 768, c4 = (t % 768) * 4;
  float4 s = {0.f, 0.f, 0.f, 0.f};
  const float* p = part + (size_t)row * 3072 + c4;
  #pragma unroll
  for (int z = 0; z < 4; ++z) {
    float4 v = *(const float4*)(p + (size_t)z * 786432);
    s.x += v.x; s.y += v.y; s.z += v.z; s.w += v.w;
  }
  if (c4 < 1536) {
    short4 o = { f2bf(s.x), f2bf(s.y), f2bf(s.z), f2bf(s.w) };
    *(short4*)(kbf + (size_t)row * 1536 + c4) = o;
  } else {
    int b = row >> 7, j = row & 127, c = c4 - 1536;
    vtbf[((size_t)(b * 1536 + c + 0)) * 128 + j] = f2bf(s.x);
    vtbf[((size_t)(b * 1536 + c + 1)) * 128 + j] = f2bf(s.y);
    vtbf[((size_t)(b * 1536 + c + 2)) * 128 + j] = f2bf(s.z);
    vtbf[((size_t)(b * 1536 + c + 3)) * 128 + j] = f2bf(s.w);
  }
}

// ---------------- fused attention for one (i-tile=128, head, batch) ----------------
// LDS 48KB: kT [0,16K), vT [16K,32K), P: waves 0/1 alias dead kT, waves 2/3 at [32K,48K)
__global__ __launch_bounds__(256, 3) void attn_k(
    const short* __restrict__ q, const short* __restrict__ kk,
    const short* __restrict__ vt, const float* __restrict__ bias,
    short* __restrict__ ao)
{
  __shared__ char sm_[49152];
  const int it = blockIdx.x, h = blockIdx.y, b = blockIdx.z;
  const int wid = threadIdx.x >> 6, lane = threadIdx.x & 63;
  const int i0 = it * 128;
  char* kT = sm_;
  char* vT = sm_ + 16384;
  char* pB = (wid < 2) ? (sm_ + wid * 8192) : (sm_ + 16384 + wid * 8192);

  #pragma unroll
  for (int c = 0; c < 4; ++c) {
    int seg = c * 256 + wid * 64 + lane;
    int j = seg >> 3, ds = seg & 7;
    int dsrc = ds ^ (j & 7);
    gl_lds16(kk + ((size_t)(b * 128 + j) * 1536 + h * 64 + dsrc * 8),
             kT + c * 4096 + wid * 1024);
  }
  #pragma unroll
  for (int c = 0; c < 4; ++c) {
    int seg = c * 256 + wid * 64 + lane;
    int d = seg >> 4, js = seg & 15;
    int jsrc = js ^ (d & 7);
    gl_lds16(vt + ((size_t)(b * 1536 + h * 64 + d) * 128 + jsrc * 8),
             vT + c * 4096 + wid * 1024);
  }

  float bcol[8];
  #pragma unroll
  for (int nj = 0; nj < 8; ++nj) bcol[nj] = bias[b * 128 + nj * 16 + (lane & 15)];

  s8bf qf[2][2];
  #pragma unroll
  for (int mi = 0; mi < 2; ++mi)
    #pragma unroll
    for (int ks = 0; ks < 2; ++ks) {
      size_t row = (size_t)(b * 4096 + i0 + wid * 32 + mi * 16 + (lane & 15));
      qf[mi][ks] = *(const s8bf*)(q + row * 1536 + h * 64 + ks * 32 + (lane >> 4) * 8);
    }
  __syncthreads();

  f32x4 s[2][8] = {};
  #pragma unroll
  for (int ks = 0; ks < 2; ++ks) {
    int kd = ks * 32 + (lane >> 4) * 8;
    #pragma unroll
    for (int nj = 0; nj < 8; ++nj) {
      int j = nj * 16 + (lane & 15);
      s8bf kb = *(const s8bf*)(kT + j * 128 + ((2 * kd) ^ ((j & 7) << 4)));
      s[0][nj] = mfma16(qf[0][ks], kb, s[0][nj]);
      s[1][nj] = mfma16(qf[1][ks], kb, s[1][nj]);
    }
  }
  __syncthreads();   // kT handoff: all waves done with K before P overlays it

  float sm[2][4];
  #pragma unroll
  for (int mi = 0; mi < 2; ++mi)
    #pragma unroll
    for (int v = 0; v < 4; ++v) {
      float mx = -1e30f;
      #pragma unroll
      for (int nj = 0; nj < 8; ++nj) {
        float sv = s[mi][nj][v] * 0.125f + bcol[nj];
        s[mi][nj][v] = sv;
        mx = fmaxf(mx, sv);
      }
      mx = fmaxf(mx, __shfl_xor(mx, 1));
      mx = fmaxf(mx, __shfl_xor(mx, 2));
      mx = fmaxf(mx, __shfl_xor(mx, 4));
      mx = fmaxf(mx, __shfl_xor(mx, 8));
      float ss = 0.f;
      #pragma unroll
      for (int nj = 0; nj < 8; ++nj) {
        float p = __expf(s[mi][nj][v] - mx);
        s[mi][nj][v] = p;
        ss += p;
      }
      ss += __shfl_xor(ss, 1);
      ss += __shfl_xor(ss, 2);
      ss += __shfl_xor(ss, 4);
      ss += __shfl_xor(ss, 8);
      sm[mi][v] = ss;
    }

  #pragma unroll
  for (int mi = 0; mi < 2; ++mi)
    #pragma unroll
    for (int v = 0; v < 4; ++v) {
      int r = mi * 16 + ((lane >> 4) << 2) + v;
      char* base = pB + r * 256;
      #pragma unroll
      for (int nj = 0; nj < 8; ++nj) {
        int j = nj * 16 + (lane & 15);
        *(short*)(base + ((2 * j) ^ ((r & 7) << 4))) = f2bf(s[mi][nj][v]);
      }
    }
  __syncthreads();

  f32x4 o_[2][4] = {};
  #pragma unroll
  for (int ks = 0; ks < 4; ++ks) {
    int j = ks * 32 + (lane >> 4) * 8;
    s8bf pa[2];
    #pragma unroll
    for (int mi = 0; mi < 2; ++mi) {
      int r = mi * 16 + (lane & 15);
      pa[mi] = *(const s8bf*)(pB + r * 256 + ((2 * j) ^ ((r & 7) << 4)));
    }
    #pragma unroll
    for (int dj = 0; dj < 4; ++dj) {
      int d = dj * 16 + (lane & 15);
      s8bf vb = *(const s8bf*)(vT + d * 256 + ((2 * j) ^ ((d & 7) << 4)));
      o_[0][dj] = mfma16(pa[0], vb, o_[0][dj]);
      o_[1][dj] = mfma16(pa[1], vb, o_[1][dj]);
    }
  }

  #pragma unroll
  for (int mi = 0; mi < 2; ++mi)
    #pragma unroll
    for (int v = 0; v < 4; ++v) {
      int r = mi * 16 + ((lane >> 4) << 2) + v;
      float is = 1.0f / sm[mi][v];
      size_t row = (size_t)(b * 4096 + i0 + wid * 32 + r);
      #pragma unroll
      for (int dj = 0; dj < 4; ++dj) {
        int d = dj * 16 + (lane & 15);
        ao[row * 1536 + h * 64 + d] = f2bf(o_[mi][dj][v] * is);
      }
    }
}

extern "C" void kernel_launch(void* const* d_in, const int* in_sizes, int n_in,
                              void* d_out, int out_size, void* d_ws, size_t ws_size,
                              hipStream_t stream) {
  const float* x   = (const float*)d_in[0];
  const float* ctx = (const float*)d_in[1];
  const void*  msk = d_in[2];
  const float* Wq  = (const float*)d_in[3];
  const float* Wk  = (const float*)d_in[4];
  const float* Wv  = (const float*)d_in[5];
  const float* Wo  = (const float*)d_in[6];
  float* out = (float*)d_out;

  const int B = 2, NI = 4096, NT = 128, C = 1536, CC = 4096, H = 24;
  const int Mq = B * NI;  // 8192
  const int Mk = B * NT;  // 256

  size_t off = 0;
  auto carve = [&](size_t bytes) -> void* {
    void* p = (char*)d_ws + off;
    off += (bytes + 255) & ~(size_t)255;
    return p;
  };
  short* xbf   = (short*)carve((size_t)Mq * C * 2);   // reused as attn-out after Q-proj
  short* ctxbf = (short*)carve((size_t)Mk * CC * 2);
  short* WqT   = (short*)carve((size_t)C * C * 2);
  short* WkT   = (short*)carve((size_t)CC * C * 2);   // WvT must follow contiguously
  short* WvT   = (short*)carve((size_t)CC * C * 2);
  short* WoT   = (short*)carve((size_t)C * C * 2);
  short* qbf   = (short*)carve((size_t)Mq * C * 2);
  short* kbf   = (short*)carve((size_t)Mk * C * 2);
  short* vtbf  = (short*)carve((size_t)Mk * C * 2);
  float* bias  = (float*)carve(256 * 4);
  short* aout  = xbf;            // alias: x dead after Q-proj
  float* part  = out;            // d_out as split-K scratch (12.6MB, fully overwritten later)

  // allow 128KB dynamic LDS on the pipelined GEMMs (idempotent, capture-safe)
  hipFuncSetAttribute((const void*)gemm32_k<0>, hipFuncAttributeMaxDynamicSharedMemorySize, 131072);
  hipFuncSetAttribute((const void*)gemm32_k<1>, hipFuncAttributeMaxDynamicSharedMemorySize, 131072);

  // pre-pass
  cvt_f32_bf16_k<<<(Mq * C / 4 + 255) / 256, 256, 0, stream>>>(x, xbf, Mq * C / 4);
  cvt_f32_bf16_k<<<(Mk * CC / 4 + 255) / 256, 256, 0, stream>>>(ctx, ctxbf, Mk * CC / 4);
  transp_bf16_k<<<dim3(C / 32, C / 32), 256, 0, stream>>>(Wq, WqT, C, C);
  transp_bf16_k<<<dim3(CC / 32, C / 32), 256, 0, stream>>>(Wk, WkT, CC, C);
  transp_bf16_k<<<dim3(CC / 32, C / 32), 256, 0, stream>>>(Wv, WvT, CC, C);
  transp_bf16_k<<<dim3(C / 32, C / 32), 256, 0, stream>>>(Wo, WoT, C, C);
  mask_bias_k<<<1, 256, 0, stream>>>(msk, bias, 256);

  // Q projection (32x32-MFMA pipelined GEMM, bf16 out): grid 32x6 = 192
  gemm32_k<0><<<(Mq / 256) * (C / 256), 512, 131072, stream>>>(xbf, WqT, qbf, Mq, C, C);
  // K+V projections merged: split-K=4 f32 partials into d_out scratch, then reduce
  gemm_bt_k<5><<<dim3(Mk / 128, 3072 / 128, 4), 256, 0, stream>>>(ctxbf, WkT, part, Mk, 3072, CC, 1024);
  kv_reduce_k<<<768, 256, 0, stream>>>(part, kbf, vtbf);

  // fused attention
  attn_k<<<dim3(NI / 128, H, B), 256, 0, stream>>>(qbf, kbf, vtbf, bias, aout);

  // output projection (32x32-MFMA pipelined GEMM, f32 out)
  gemm32_k<1><<<(Mq / 256) * (C / 256), 512, 131072, stream>>>(aout, WoT, out, Mq, C, C);
}

// Round 10
// 175.924 us; speedup vs baseline: 1.3070x; 1.3070x over previous
//
#include <hip/hip_runtime.h>

typedef __attribute__((ext_vector_type(8))) short s8bf;     // 8 bf16 payload
typedef __attribute__((ext_vector_type(8))) __bf16 v8bf;    // MFMA operand type
typedef __attribute__((ext_vector_type(4))) float f32x4;

__device__ __forceinline__ short f2bf(float f) {
  union { float f; unsigned u; } v; v.f = f;
  unsigned r = v.u + 0x7FFFu + ((v.u >> 16) & 1u);  // RNE
  return (short)(r >> 16);
}

__device__ __forceinline__ f32x4 mfma16(s8bf a, s8bf b, f32x4 c) {
  return __builtin_amdgcn_mfma_f32_16x16x32_bf16(
      __builtin_bit_cast(v8bf, a), __builtin_bit_cast(v8bf, b), c, 0, 0, 0);
}

__device__ __forceinline__ void gl_lds16(const void* g, void* l) {
  __builtin_amdgcn_global_load_lds(
      (const __attribute__((address_space(1))) unsigned*)g,
      (__attribute__((address_space(3))) unsigned*)l, 16, 0, 0);
}

// ======== fused pre-pass: x cast | ctx cast | 4 weight transposes | mask ========
// One launch replaces 7. Job decode by blockIdx.x; per-job bodies byte-identical
// to the r7 standalone kernels. Grid = 30209 blocks x 256 thr.
__global__ __launch_bounds__(256) void prep_k(
    const float* __restrict__ x, const float* __restrict__ ctx,
    const void* __restrict__ msk,
    const float* __restrict__ Wq, const float* __restrict__ Wk,
    const float* __restrict__ Wv, const float* __restrict__ Wo,
    short* __restrict__ xbf, short* __restrict__ ctxbf,
    short* __restrict__ WqT, short* __restrict__ WkT,
    short* __restrict__ WvT, short* __restrict__ WoT,
    float* __restrict__ bias)
{
  __shared__ float tile[32][33];
  __shared__ int fmt;
  const int blk = blockIdx.x;
  if (blk < 12288) {                       // ---- x cast: 3,145,728 float4
    int i = blk * 256 + threadIdx.x;
    float4 v = ((const float4*)x)[i];
    short4 o = { f2bf(v.x), f2bf(v.y), f2bf(v.z), f2bf(v.w) };
    ((short4*)xbf)[i] = o;
  } else if (blk < 13312) {                // ---- ctx cast: 262,144 float4
    int i = (blk - 12288) * 256 + threadIdx.x;
    float4 v = ((const float4*)ctx)[i];
    short4 o = { f2bf(v.x), f2bf(v.y), f2bf(v.z), f2bf(v.w) };
    ((short4*)ctxbf)[i] = o;
  } else if (blk < 30208) {                // ---- weight transposes
    int t = blk - 13312;
    const float* W; short* Wt; int K, t0;
    if (t < 2304)       { W = Wq; Wt = WqT; K = 1536; t0 = t; }
    else if (t < 8448)  { W = Wk; Wt = WkT; K = 4096; t0 = t - 2304; }
    else if (t < 14592) { W = Wv; Wt = WvT; K = 4096; t0 = t - 8448; }
    else                { W = Wo; Wt = WoT; K = 1536; t0 = t - 14592; }
    const int N = 1536;
    int ntx = K / 32;
    int k0 = (t0 % ntx) * 32, n0 = (t0 / ntx) * 32;
    int tx = threadIdx.x & 31, ty = threadIdx.x >> 5;
    #pragma unroll
    for (int i = 0; i < 4; ++i)
      tile[ty + i * 8][tx] = W[(size_t)(k0 + ty + i * 8) * N + n0 + tx];
    __syncthreads();
    #pragma unroll
    for (int i = 0; i < 4; ++i)
      Wt[(size_t)(n0 + ty + i * 8) * K + k0 + tx] = f2bf(tile[tx][ty + i * 8]);
  } else {                                 // ---- mask -> bias (1 block)
    const unsigned char* p8 = (const unsigned char*)msk;
    if (threadIdx.x == 0) {
      const float* pf = (const float*)msk;
      int allf = 1, anyone = 0;
      for (int i = 0; i < 64; ++i) {
        float f = pf[i];
        if (f != 0.0f && f != 1.0f) allf = 0;
        if (f == 1.0f) anyone = 1;
      }
      int any13 = 0;
      for (int i = 0; i < 256; ++i) if ((i & 3) && p8[i]) any13 = 1;
      fmt = (allf && anyone) ? 2 : (any13 ? 0 : 1);
    }
    __syncthreads();
    int j = threadIdx.x;
    if (j < 256) {
      int m;
      if (fmt == 2)      m = (((const float*)msk)[j] != 0.0f);
      else if (fmt == 0) m = (p8[j] != 0);
      else               m = (((const int*)msk)[j] != 0);
      bias[j] = m ? 0.0f : -1e30f;
    }
  }
}

// ======== 4-phase GEMM, r7-verified (0 conflicts): BM=256 BN=192, full coverage ========
// A[M][K] bf16 @ Bt[N][K]^T -> C[M][N].  MODE 0: bf16 store, 1: f32 store.
// LDS per buffer (56KB): A0@0(16K) A1@16K B0@32K(12K) B1@45056(12K); bufs 0/57344.
// Subtile = lines of 128B; line L = rows {2L,2L+1} of the k-half, 8x16B slots.
// Swizzle: phys slot = logical slot ^ (line&7), logical slot = 4*(row&1)+col16.
// Stage instrs: A k-half = 2x8KB (512 thr); B k-half = 8KB (512 thr) + 4KB (wid<4).
// Ledger: wid<4 issues 8 stage-instrs/tile, wid>=4 issues 6; boundary vmcnt(8)/(6)
// proves the two subtiles the next phases read have landed. In-flight never drains.
template<int MODE>
__global__ __launch_bounds__(512, 2) void gemm4ph_k(
    const short* __restrict__ A, const short* __restrict__ Bt, void* __restrict__ C,
    int M, int N, int K)
{
  extern __shared__ char ldsb[];
  const int tid = threadIdx.x, wid = tid >> 6, lane = tid & 63;
  const int nbx = N / 192;
  const int nwg = gridDim.x, bid = blockIdx.x;
  const int swz = (bid & 7) * (nwg >> 3) + (bid >> 3);   // nwg % 8 == 0
  const int m0 = (swz / nbx) * 256, n0 = (swz % nbx) * 192;
  const int wm = wid >> 2, wn = wid & 3;
  const int NT = K / 64;

  const int l = lane & 15, h = lane >> 4;
  const int rdslot = (((l & 1) * 4 + h) ^ (l >> 1)) * 16;
  int aoff[8], boff[3];
  #pragma unroll
  for (int mf = 0; mf < 8; ++mf)
    aoff[mf] = (wm * 64 + mf * 8 + (l >> 1)) * 128 + rdslot;
  #pragma unroll
  for (int nf = 0; nf < 3; ++nf)
    boff[nf] = 32768 + (wn * 24 + nf * 8 + (l >> 1)) * 128 + rdslot;

  const int ls = (tid & 7) ^ ((tid >> 3) & 7);
  const int srow2 = 2 * (tid >> 3) + (ls >> 2);
  const int scol = (ls & 3) * 8;
  const short* sA_lo = A  + (size_t)(m0 + srow2) * K + scol;
  const short* sA_hi = A  + (size_t)(m0 + 128 + srow2) * K + scol;
  const short* sB_lo = Bt + (size_t)(n0 + srow2) * K + scol;
  const short* sB_hi = Bt + (size_t)(n0 + 128 + srow2) * K + scol;
  const int d16 = tid * 16;

  f32x4 acc[8][3] = {};
  s8bf av[4], av2[4], bk[3];

  gl_lds16(sA_lo,      ldsb + 0     + d16);
  gl_lds16(sA_hi,      ldsb + 8192  + d16);
  gl_lds16(sB_lo,      ldsb + 32768 + d16);
  if (wid < 4) gl_lds16(sB_hi,      ldsb + 40960 + d16);
  gl_lds16(sA_lo + 32, ldsb + 16384 + d16);
  gl_lds16(sA_hi + 32, ldsb + 24576 + d16);
  gl_lds16(sB_lo + 32, ldsb + 45056 + d16);
  if (wid < 4) gl_lds16(sB_hi + 32, ldsb + 53248 + d16);
  gl_lds16(sA_lo + 64, ldsb + 57344 + 0     + d16);
  gl_lds16(sA_hi + 64, ldsb + 57344 + 8192  + d16);
  gl_lds16(sB_lo + 64, ldsb + 57344 + 32768 + d16);
  if (wid < 4) gl_lds16(sB_hi + 64, ldsb + 57344 + 40960 + d16);
  if (wid < 4) asm volatile("s_waitcnt vmcnt(8)" ::: "memory");
  else         asm volatile("s_waitcnt vmcnt(6)" ::: "memory");
  __builtin_amdgcn_s_barrier();

  for (int t = 0; t < NT; ++t) {
    const int bo = (t & 1) * 57344, bo2 = bo ^ 57344;
    const int kt1 = ((t + 1) < NT ? (t + 1) : (NT - 1)) * 64;
    const int kt2 = ((t + 2) < NT ? (t + 2) : (NT - 1)) * 64;
    // ---- phase 0
    #pragma unroll
    for (int i = 0; i < 4; ++i) av[i] = *(const s8bf*)(ldsb + bo + aoff[i]);
    #pragma unroll
    for (int nf = 0; nf < 3; ++nf) bk[nf] = *(const s8bf*)(ldsb + bo + boff[nf]);
    gl_lds16(sA_lo + kt1 + 32, ldsb + bo2 + 16384 + d16);
    gl_lds16(sA_hi + kt1 + 32, ldsb + bo2 + 24576 + d16);
    __builtin_amdgcn_s_barrier();
    asm volatile("s_waitcnt lgkmcnt(0)" ::: "memory");
    __builtin_amdgcn_s_setprio(1);
    #pragma unroll
    for (int i = 0; i < 4; ++i)
      #pragma unroll
      for (int nf = 0; nf < 3; ++nf)
        acc[i][nf] = mfma16(av[i], bk[nf], acc[i][nf]);
    __builtin_amdgcn_s_setprio(0);
    __builtin_amdgcn_s_barrier();
    // ---- phase 1
    #pragma unroll
    for (int i = 0; i < 4; ++i) av2[i] = *(const s8bf*)(ldsb + bo + aoff[4 + i]);
    gl_lds16(sB_lo + kt1 + 32, ldsb + bo2 + 45056 + d16);
    if (wid < 4) gl_lds16(sB_hi + kt1 + 32, ldsb + bo2 + 53248 + d16);
    __builtin_amdgcn_s_barrier();
    asm volatile("s_waitcnt lgkmcnt(0)" ::: "memory");
    __builtin_amdgcn_s_setprio(1);
    #pragma unroll
    for (int i = 0; i < 4; ++i)
      #pragma unroll
      for (int nf = 0; nf < 3; ++nf)
        acc[4 + i][nf] = mfma16(av2[i], bk[nf], acc[4 + i][nf]);
    __builtin_amdgcn_s_setprio(0);
    if (wid < 4) asm volatile("s_waitcnt vmcnt(8)" ::: "memory");
    else         asm volatile("s_waitcnt vmcnt(6)" ::: "memory");
    __builtin_amdgcn_s_barrier();
    // ---- phase 2
    #pragma unroll
    for (int i = 0; i < 4; ++i) av[i] = *(const s8bf*)(ldsb + bo + 16384 + aoff[i]);
    #pragma unroll
    for (int nf = 0; nf < 3; ++nf) bk[nf] = *(const s8bf*)(ldsb + bo + 12288 + boff[nf]);
    gl_lds16(sA_lo + kt2, ldsb + bo + 0    + d16);
    gl_lds16(sA_hi + kt2, ldsb + bo + 8192 + d16);
    __builtin_amdgcn_s_barrier();
    asm volatile("s_waitcnt lgkmcnt(0)" ::: "memory");
    __builtin_amdgcn_s_setprio(1);
    #pragma unroll
    for (int i = 0; i < 4; ++i)
      #pragma unroll
      for (int nf = 0; nf < 3; ++nf)
        acc[i][nf] = mfma16(av[i], bk[nf], acc[i][nf]);
    __builtin_amdgcn_s_setprio(0);
    __builtin_amdgcn_s_barrier();
    // ---- phase 3
    #pragma unroll
    for (int i = 0; i < 4; ++i) av2[i] = *(const s8bf*)(ldsb + bo + 16384 + aoff[4 + i]);
    gl_lds16(sB_lo + kt2, ldsb + bo + 32768 + d16);
    if (wid < 4) gl_lds16(sB_hi + kt2, ldsb + bo + 40960 + d16);
    __builtin_amdgcn_s_barrier();
    asm volatile("s_waitcnt lgkmcnt(0)" ::: "memory");
    __builtin_amdgcn_s_setprio(1);
    #pragma unroll
    for (int i = 0; i < 4; ++i)
      #pragma unroll
      for (int nf = 0; nf < 3; ++nf)
        acc[4 + i][nf] = mfma16(av2[i], bk[nf], acc[4 + i][nf]);
    __builtin_amdgcn_s_setprio(0);
    if (wid < 4) asm volatile("s_waitcnt vmcnt(8)" ::: "memory");
    else         asm volatile("s_waitcnt vmcnt(6)" ::: "memory");
    __builtin_amdgcn_s_barrier();
  }
  asm volatile("s_waitcnt vmcnt(0)" ::: "memory");

  const int r0 = m0 + wm * 128 + ((lane >> 4) << 2);
  const int c0 = n0 + wn * 48 + (lane & 15);
  #pragma unroll
  for (int mf = 0; mf < 8; ++mf)
    #pragma unroll
    for (int nf = 0; nf < 3; ++nf)
      #pragma unroll
      for (int v = 0; v < 4; ++v) {
        int row = r0 + mf * 16 + v, col = c0 + nf * 16;
        float val = acc[mf][nf][v];
        if (MODE == 0) ((short*)C)[(size_t)row * N + col] = f2bf(val);
        else           ((float*)C)[(size_t)row * N + col] = val;
      }
}

// ---------------- m97-style GEMM for split-K K/V projection ----------------
// MODE 5: per-slice f32 partial store (no atomics): C[z][row][col], slice stride 256*3072
template<int MODE>
__global__ __launch_bounds__(256, 2) void gemm_bt_k(
    const short* __restrict__ A, const short* __restrict__ Bt, void* __restrict__ C,
    int M, int N, int K, int kchunk)
{
  __shared__ short aT[128 * 32];
  __shared__ short bT[128 * 32];
  const int m0 = blockIdx.x * 128, n0 = blockIdx.y * 128;
  const int wid = threadIdx.x >> 6, lane = threadIdx.x & 63;
  const int wr = wid >> 1, wc = wid & 1;
  const int k_lo = blockIdx.z * kchunk, k_hi = k_lo + kchunk;
  f32x4 acc[4][4] = {};
  const int srow = wid * 32 + (lane >> 2);
  const int skoff = (lane & 3) * 8;
  const short* aG = A + (size_t)(m0 + srow) * K + skoff;
  const short* bG = Bt + (size_t)(n0 + srow) * K + skoff;
  char* aL = (char*)aT + wid * 2048;
  char* bL = (char*)bT + wid * 2048;
  const short* ap = aT + (wr * 64 + (lane & 15)) * 32 + (lane >> 4) * 8;
  const short* bp = bT + (wc * 64 + (lane & 15)) * 32 + (lane >> 4) * 8;
  for (int k0 = k_lo; k0 < k_hi; k0 += 32) {
    gl_lds16(aG + k0, aL);
    gl_lds16(aG + (size_t)16 * K + k0, aL + 1024);
    gl_lds16(bG + k0, bL);
    gl_lds16(bG + (size_t)16 * K + k0, bL + 1024);
    __syncthreads();
    s8bf af[4], bf[4];
    #pragma unroll
    for (int i = 0; i < 4; ++i) {
      af[i] = *(const s8bf*)(ap + i * 512);
      bf[i] = *(const s8bf*)(bp + i * 512);
    }
    #pragma unroll
    for (int mi = 0; mi < 4; ++mi)
      #pragma unroll
      for (int ni = 0; ni < 4; ++ni)
        acc[mi][ni] = mfma16(af[mi], bf[ni], acc[mi][ni]);
    __syncthreads();
  }
  const int r0 = m0 + wr * 64 + ((lane >> 4) << 2);
  const int c0 = n0 + wc * 64 + (lane & 15);
  float* Cf = (float*)C + (size_t)blockIdx.z * 786432;
  #pragma unroll
  for (int mi = 0; mi < 4; ++mi)
    #pragma unroll
    for (int ni = 0; ni < 4; ++ni)
      #pragma unroll
      for (int v = 0; v < 4; ++v) {
        int row = r0 + mi * 16 + v, col = c0 + ni * 16;
        Cf[(size_t)row * N + col] = acc[mi][ni][v];
      }
}

// ---------------- reduce 4 split-K slices -> bf16 K (row-major) + V^T ----------------
__global__ void kv_reduce_k(const float* __restrict__ part, short* __restrict__ kbf,
                            short* __restrict__ vtbf) {
  int t = blockIdx.x * 256 + threadIdx.x;          // t < 196608
  int row = t / 768, c4 = (t % 768) * 4;
  float4 s = {0.f, 0.f, 0.f, 0.f};
  const float* p = part + (size_t)row * 3072 + c4;
  #pragma unroll
  for (int z = 0; z < 4; ++z) {
    float4 v = *(const float4*)(p + (size_t)z * 786432);
    s.x += v.x; s.y += v.y; s.z += v.z; s.w += v.w;
  }
  if (c4 < 1536) {
    short4 o = { f2bf(s.x), f2bf(s.y), f2bf(s.z), f2bf(s.w) };
    *(short4*)(kbf + (size_t)row * 1536 + c4) = o;
  } else {
    int b = row >> 7, j = row & 127, c = c4 - 1536;
    vtbf[((size_t)(b * 1536 + c + 0)) * 128 + j] = f2bf(s.x);
    vtbf[((size_t)(b * 1536 + c + 1)) * 128 + j] = f2bf(s.y);
    vtbf[((size_t)(b * 1536 + c + 2)) * 128 + j] = f2bf(s.z);
    vtbf[((size_t)(b * 1536 + c + 3)) * 128 + j] = f2bf(s.w);
  }
}

// ---------------- fused attention for one (i-tile=128, head, batch) ----------------
// LDS 48KB: kT [0,16K), vT [16K,32K), P: waves 0/1 alias dead kT, waves 2/3 at [32K,48K)
__global__ __launch_bounds__(256, 3) void attn_k(
    const short* __restrict__ q, const short* __restrict__ kk,
    const short* __restrict__ vt, const float* __restrict__ bias,
    short* __restrict__ ao)
{
  __shared__ char sm_[49152];
  const int it = blockIdx.x, h = blockIdx.y, b = blockIdx.z;
  const int wid = threadIdx.x >> 6, lane = threadIdx.x & 63;
  const int i0 = it * 128;
  char* kT = sm_;
  char* vT = sm_ + 16384;
  char* pB = (wid < 2) ? (sm_ + wid * 8192) : (sm_ + 16384 + wid * 8192);

  #pragma unroll
  for (int c = 0; c < 4; ++c) {
    int seg = c * 256 + wid * 64 + lane;
    int j = seg >> 3, ds = seg & 7;
    int dsrc = ds ^ (j & 7);
    gl_lds16(kk + ((size_t)(b * 128 + j) * 1536 + h * 64 + dsrc * 8),
             kT + c * 4096 + wid * 1024);
  }
  #pragma unroll
  for (int c = 0; c < 4; ++c) {
    int seg = c * 256 + wid * 64 + lane;
    int d = seg >> 4, js = seg & 15;
    int jsrc = js ^ (d & 7);
    gl_lds16(vt + ((size_t)(b * 1536 + h * 64 + d) * 128 + jsrc * 8),
             vT + c * 4096 + wid * 1024);
  }

  float bcol[8];
  #pragma unroll
  for (int nj = 0; nj < 8; ++nj) bcol[nj] = bias[b * 128 + nj * 16 + (lane & 15)];

  s8bf qf[2][2];
  #pragma unroll
  for (int mi = 0; mi < 2; ++mi)
    #pragma unroll
    for (int ks = 0; ks < 2; ++ks) {
      size_t row = (size_t)(b * 4096 + i0 + wid * 32 + mi * 16 + (lane & 15));
      qf[mi][ks] = *(const s8bf*)(q + row * 1536 + h * 64 + ks * 32 + (lane >> 4) * 8);
    }
  __syncthreads();

  f32x4 s[2][8] = {};
  #pragma unroll
  for (int ks = 0; ks < 2; ++ks) {
    int kd = ks * 32 + (lane >> 4) * 8;
    #pragma unroll
    for (int nj = 0; nj < 8; ++nj) {
      int j = nj * 16 + (lane & 15);
      s8bf kb = *(const s8bf*)(kT + j * 128 + ((2 * kd) ^ ((j & 7) << 4)));
      s[0][nj] = mfma16(qf[0][ks], kb, s[0][nj]);
      s[1][nj] = mfma16(qf[1][ks], kb, s[1][nj]);
    }
  }
  __syncthreads();   // kT handoff: all waves done with K before P overlays it

  float sm[2][4];
  #pragma unroll
  for (int mi = 0; mi < 2; ++mi)
    #pragma unroll
    for (int v = 0; v < 4; ++v) {
      float mx = -1e30f;
      #pragma unroll
      for (int nj = 0; nj < 8; ++nj) {
        float sv = s[mi][nj][v] * 0.125f + bcol[nj];
        s[mi][nj][v] = sv;
        mx = fmaxf(mx, sv);
      }
      mx = fmaxf(mx, __shfl_xor(mx, 1));
      mx = fmaxf(mx, __shfl_xor(mx, 2));
      mx = fmaxf(mx, __shfl_xor(mx, 4));
      mx = fmaxf(mx, __shfl_xor(mx, 8));
      float ss = 0.f;
      #pragma unroll
      for (int nj = 0; nj < 8; ++nj) {
        float p = __expf(s[mi][nj][v] - mx);
        s[mi][nj][v] = p;
        ss += p;
      }
      ss += __shfl_xor(ss, 1);
      ss += __shfl_xor(ss, 2);
      ss += __shfl_xor(ss, 4);
      ss += __shfl_xor(ss, 8);
      sm[mi][v] = ss;
    }

  #pragma unroll
  for (int mi = 0; mi < 2; ++mi)
    #pragma unroll
    for (int v = 0; v < 4; ++v) {
      int r = mi * 16 + ((lane >> 4) << 2) + v;
      char* base = pB + r * 256;
      #pragma unroll
      for (int nj = 0; nj < 8; ++nj) {
        int j = nj * 16 + (lane & 15);
        *(short*)(base + ((2 * j) ^ ((r & 7) << 4))) = f2bf(s[mi][nj][v]);
      }
    }
  __syncthreads();

  f32x4 o_[2][4] = {};
  #pragma unroll
  for (int ks = 0; ks < 4; ++ks) {
    int j = ks * 32 + (lane >> 4) * 8;
    s8bf pa[2];
    #pragma unroll
    for (int mi = 0; mi < 2; ++mi) {
      int r = mi * 16 + (lane & 15);
      pa[mi] = *(const s8bf*)(pB + r * 256 + ((2 * j) ^ ((r & 7) << 4)));
    }
    #pragma unroll
    for (int dj = 0; dj < 4; ++dj) {
      int d = dj * 16 + (lane & 15);
      s8bf vb = *(const s8bf*)(vT + d * 256 + ((2 * j) ^ ((d & 7) << 4)));
      o_[0][dj] = mfma16(pa[0], vb, o_[0][dj]);
      o_[1][dj] = mfma16(pa[1], vb, o_[1][dj]);
    }
  }

  #pragma unroll
  for (int mi = 0; mi < 2; ++mi)
    #pragma unroll
    for (int v = 0; v < 4; ++v) {
      int r = mi * 16 + ((lane >> 4) << 2) + v;
      float is = 1.0f / sm[mi][v];
      size_t row = (size_t)(b * 4096 + i0 + wid * 32 + r);
      #pragma unroll
      for (int dj = 0; dj < 4; ++dj) {
        int d = dj * 16 + (lane & 15);
        ao[row * 1536 + h * 64 + d] = f2bf(o_[mi][dj][v] * is);
      }
    }
}

extern "C" void kernel_launch(void* const* d_in, const int* in_sizes, int n_in,
                              void* d_out, int out_size, void* d_ws, size_t ws_size,
                              hipStream_t stream) {
  const float* x   = (const float*)d_in[0];
  const float* ctx = (const float*)d_in[1];
  const void*  msk = d_in[2];
  const float* Wq  = (const float*)d_in[3];
  const float* Wk  = (const float*)d_in[4];
  const float* Wv  = (const float*)d_in[5];
  const float* Wo  = (const float*)d_in[6];
  float* out = (float*)d_out;

  const int B = 2, NI = 4096, NT = 128, C = 1536, CC = 4096, H = 24;
  const int Mq = B * NI;  // 8192
  const int Mk = B * NT;  // 256

  size_t off = 0;
  auto carve = [&](size_t bytes) -> void* {
    void* p = (char*)d_ws + off;
    off += (bytes + 255) & ~(size_t)255;
    return p;
  };
  short* xbf   = (short*)carve((size_t)Mq * C * 2);   // reused as attn-out after Q-proj
  short* ctxbf = (short*)carve((size_t)Mk * CC * 2);
  short* WqT   = (short*)carve((size_t)C * C * 2);
  short* WkT   = (short*)carve((size_t)CC * C * 2);   // WvT must follow contiguously
  short* WvT   = (short*)carve((size_t)CC * C * 2);
  short* WoT   = (short*)carve((size_t)C * C * 2);
  short* qbf   = (short*)carve((size_t)Mq * C * 2);
  short* kbf   = (short*)carve((size_t)Mk * C * 2);
  short* vtbf  = (short*)carve((size_t)Mk * C * 2);
  float* bias  = (float*)carve(256 * 4);
  short* aout  = xbf;            // alias: x dead after Q-proj
  float* part  = out;            // d_out as split-K scratch (12.6MB, fully overwritten later)

  // allow 112KB dynamic LDS on the pipelined GEMMs (idempotent, capture-safe)
  hipFuncSetAttribute((const void*)gemm4ph_k<0>, hipFuncAttributeMaxDynamicSharedMemorySize, 114688);
  hipFuncSetAttribute((const void*)gemm4ph_k<1>, hipFuncAttributeMaxDynamicSharedMemorySize, 114688);

  // fused pre-pass (casts + transposes + mask) in one launch
  prep_k<<<30209, 256, 0, stream>>>(x, ctx, msk, Wq, Wk, Wv, Wo,
                                    xbf, ctxbf, WqT, WkT, WvT, WoT, bias);

  // Q projection (4-phase GEMM, bf16 out): grid 32x8 = 256 (full CU coverage)
  gemm4ph_k<0><<<(Mq / 256) * (C / 192), 512, 114688, stream>>>(xbf, WqT, qbf, Mq, C, C);
  // K+V projections merged: split-K=4 f32 partials into d_out scratch, then reduce
  gemm_bt_k<5><<<dim3(Mk / 128, 3072 / 128, 4), 256, 0, stream>>>(ctxbf, WkT, part, Mk, 3072, CC, 1024);
  kv_reduce_k<<<768, 256, 0, stream>>>(part, kbf, vtbf);

  // fused attention
  attn_k<<<dim3(NI / 128, H, B), 256, 0, stream>>>(qbf, kbf, vtbf, bias, aout);

  // output projection (4-phase GEMM, f32 out)
  gemm4ph_k<1><<<(Mq / 256) * (C / 192), 512, 114688, stream>>>(aout, WoT, out, Mq, C, C);
}

// Round 11
// 169.638 us; speedup vs baseline: 1.3554x; 1.0371x over previous
//
#include <hip/hip_runtime.h>

typedef __attribute__((ext_vector_type(8))) short s8bf;     // 8 bf16 payload
typedef __attribute__((ext_vector_type(8))) __bf16 v8bf;    // MFMA operand type
typedef __attribute__((ext_vector_type(4))) float f32x4;

__device__ __forceinline__ short f2bf(float f) {
  union { float f; unsigned u; } v; v.f = f;
  unsigned r = v.u + 0x7FFFu + ((v.u >> 16) & 1u);  // RNE
  return (short)(r >> 16);
}

__device__ __forceinline__ f32x4 mfma16(s8bf a, s8bf b, f32x4 c) {
  return __builtin_amdgcn_mfma_f32_16x16x32_bf16(
      __builtin_bit_cast(v8bf, a), __builtin_bit_cast(v8bf, b), c, 0, 0, 0);
}

__device__ __forceinline__ void gl_lds16(const void* g, void* l) {
  __builtin_amdgcn_global_load_lds(
      (const __attribute__((address_space(1))) unsigned*)g,
      (__attribute__((address_space(3))) unsigned*)l, 16, 0, 0);
}

// ======== fused pre-pass v2: ILP casts + 64x64 transposes + mask ========
// Jobs by blockIdx.x: [0,3072) x cast | [3072,3328) ctx cast |
// [3328,7552) weight transposes (64x64 f32 tiles) | 7552 mask.
// Casts: 4 float4/thread unrolled (MLP=4). Transpose: tile[64][65] f32 (odd pad:
// read-phase banks (8kc+j+n)%32 = exact 2-way = free); store 8 k-consecutive bf16
// per thread as one 16B write. Output bytes identical to the r10 pre-pass.
__global__ __launch_bounds__(256) void prep_k(
    const float* __restrict__ x, const float* __restrict__ ctx,
    const void* __restrict__ msk,
    const float* __restrict__ Wq, const float* __restrict__ Wk,
    const float* __restrict__ Wv, const float* __restrict__ Wo,
    short* __restrict__ xbf, short* __restrict__ ctxbf,
    short* __restrict__ WqT, short* __restrict__ WkT,
    short* __restrict__ WvT, short* __restrict__ WoT,
    float* __restrict__ bias)
{
  __shared__ float tile[64][65];
  __shared__ int fmt;
  const int blk = blockIdx.x;
  if (blk < 3328) {                        // ---- casts (x: 3072 blocks, ctx: 256)
    const float4* src;
    short4* dst;
    if (blk < 3072) { src = (const float4*)x + (size_t)blk * 1024;
                      dst = (short4*)xbf + (size_t)blk * 1024; }
    else            { src = (const float4*)ctx + (size_t)(blk - 3072) * 1024;
                      dst = (short4*)ctxbf + (size_t)(blk - 3072) * 1024; }
    float4 v0 = src[threadIdx.x];
    float4 v1 = src[threadIdx.x + 256];
    float4 v2 = src[threadIdx.x + 512];
    float4 v3 = src[threadIdx.x + 768];
    short4 o0 = { f2bf(v0.x), f2bf(v0.y), f2bf(v0.z), f2bf(v0.w) };
    short4 o1 = { f2bf(v1.x), f2bf(v1.y), f2bf(v1.z), f2bf(v1.w) };
    short4 o2 = { f2bf(v2.x), f2bf(v2.y), f2bf(v2.z), f2bf(v2.w) };
    short4 o3 = { f2bf(v3.x), f2bf(v3.y), f2bf(v3.z), f2bf(v3.w) };
    dst[threadIdx.x]       = o0;
    dst[threadIdx.x + 256] = o1;
    dst[threadIdx.x + 512] = o2;
    dst[threadIdx.x + 768] = o3;
  } else if (blk < 7552) {                 // ---- weight transposes (64x64 tiles)
    int t = blk - 3328;
    const float* W; short* Wt; int K, t0;
    if (t < 576)       { W = Wq; Wt = WqT; K = 1536; t0 = t; }
    else if (t < 2112) { W = Wk; Wt = WkT; K = 4096; t0 = t - 576; }
    else if (t < 3648) { W = Wv; Wt = WvT; K = 4096; t0 = t - 2112; }
    else               { W = Wo; Wt = WoT; K = 1536; t0 = t - 3648; }
    const int N = 1536;
    int ntx = K / 64;
    int k0 = (t0 % ntx) * 64, n0 = (t0 / ntx) * 64;
    int r = threadIdx.x >> 4;              // 0..15
    int c4 = threadIdx.x & 15;             // 0..15
    #pragma unroll
    for (int i = 0; i < 4; ++i) {
      float4 v = *(const float4*)(W + (size_t)(k0 + r + i * 16) * N + n0 + c4 * 4);
      tile[r + i * 16][c4 * 4 + 0] = v.x;
      tile[r + i * 16][c4 * 4 + 1] = v.y;
      tile[r + i * 16][c4 * 4 + 2] = v.z;
      tile[r + i * 16][c4 * 4 + 3] = v.w;
    }
    __syncthreads();
    int n = threadIdx.x >> 3, kc = threadIdx.x & 7;   // n 0..31, kc 0..7
    #pragma unroll
    for (int half = 0; half < 2; ++half) {
      int nn = n + half * 32;
      s8bf o;
      #pragma unroll
      for (int j = 0; j < 8; ++j) o[j] = f2bf(tile[kc * 8 + j][nn]);
      *(s8bf*)(Wt + (size_t)(n0 + nn) * K + k0 + kc * 8) = o;
    }
  } else {                                 // ---- mask -> bias (1 block)
    const unsigned char* p8 = (const unsigned char*)msk;
    if (threadIdx.x == 0) {
      const float* pf = (const float*)msk;
      int allf = 1, anyone = 0;
      for (int i = 0; i < 64; ++i) {
        float f = pf[i];
        if (f != 0.0f && f != 1.0f) allf = 0;
        if (f == 1.0f) anyone = 1;
      }
      int any13 = 0;
      for (int i = 0; i < 256; ++i) if ((i & 3) && p8[i]) any13 = 1;
      fmt = (allf && anyone) ? 2 : (any13 ? 0 : 1);
    }
    __syncthreads();
    int j = threadIdx.x;
    if (j < 256) {
      int m;
      if (fmt == 2)      m = (((const float*)msk)[j] != 0.0f);
      else if (fmt == 0) m = (p8[j] != 0);
      else               m = (((const int*)msk)[j] != 0);
      bias[j] = m ? 0.0f : -1e30f;
    }
  }
}

// ======== 4-phase GEMM, r7-verified (0 conflicts): BM=256 BN=192, full coverage ========
// A[M][K] bf16 @ Bt[N][K]^T -> C[M][N].  MODE 0: bf16 store, 1: f32 store.
// LDS per buffer (56KB): A0@0(16K) A1@16K B0@32K(12K) B1@45056(12K); bufs 0/57344.
// Swizzle: phys slot = logical slot ^ (line&7), logical slot = 4*(row&1)+col16.
// Ledger: wid<4 issues 8 stage-instrs/tile, wid>=4 issues 6; boundary vmcnt(8)/(6).
template<int MODE>
__global__ __launch_bounds__(512, 2) void gemm4ph_k(
    const short* __restrict__ A, const short* __restrict__ Bt, void* __restrict__ C,
    int M, int N, int K)
{
  extern __shared__ char ldsb[];
  const int tid = threadIdx.x, wid = tid >> 6, lane = tid & 63;
  const int nbx = N / 192;
  const int nwg = gridDim.x, bid = blockIdx.x;
  const int swz = (bid & 7) * (nwg >> 3) + (bid >> 3);   // nwg % 8 == 0
  const int m0 = (swz / nbx) * 256, n0 = (swz % nbx) * 192;
  const int wm = wid >> 2, wn = wid & 3;
  const int NT = K / 64;

  const int l = lane & 15, h = lane >> 4;
  const int rdslot = (((l & 1) * 4 + h) ^ (l >> 1)) * 16;
  int aoff[8], boff[3];
  #pragma unroll
  for (int mf = 0; mf < 8; ++mf)
    aoff[mf] = (wm * 64 + mf * 8 + (l >> 1)) * 128 + rdslot;
  #pragma unroll
  for (int nf = 0; nf < 3; ++nf)
    boff[nf] = 32768 + (wn * 24 + nf * 8 + (l >> 1)) * 128 + rdslot;

  const int ls = (tid & 7) ^ ((tid >> 3) & 7);
  const int srow2 = 2 * (tid >> 3) + (ls >> 2);
  const int scol = (ls & 3) * 8;
  const short* sA_lo = A  + (size_t)(m0 + srow2) * K + scol;
  const short* sA_hi = A  + (size_t)(m0 + 128 + srow2) * K + scol;
  const short* sB_lo = Bt + (size_t)(n0 + srow2) * K + scol;
  const short* sB_hi = Bt + (size_t)(n0 + 128 + srow2) * K + scol;
  const int d16 = tid * 16;

  f32x4 acc[8][3] = {};
  s8bf av[4], av2[4], bk[3];

  gl_lds16(sA_lo,      ldsb + 0     + d16);
  gl_lds16(sA_hi,      ldsb + 8192  + d16);
  gl_lds16(sB_lo,      ldsb + 32768 + d16);
  if (wid < 4) gl_lds16(sB_hi,      ldsb + 40960 + d16);
  gl_lds16(sA_lo + 32, ldsb + 16384 + d16);
  gl_lds16(sA_hi + 32, ldsb + 24576 + d16);
  gl_lds16(sB_lo + 32, ldsb + 45056 + d16);
  if (wid < 4) gl_lds16(sB_hi + 32, ldsb + 53248 + d16);
  gl_lds16(sA_lo + 64, ldsb + 57344 + 0     + d16);
  gl_lds16(sA_hi + 64, ldsb + 57344 + 8192  + d16);
  gl_lds16(sB_lo + 64, ldsb + 57344 + 32768 + d16);
  if (wid < 4) gl_lds16(sB_hi + 64, ldsb + 57344 + 40960 + d16);
  if (wid < 4) asm volatile("s_waitcnt vmcnt(8)" ::: "memory");
  else         asm volatile("s_waitcnt vmcnt(6)" ::: "memory");
  __builtin_amdgcn_s_barrier();

  for (int t = 0; t < NT; ++t) {
    const int bo = (t & 1) * 57344, bo2 = bo ^ 57344;
    const int kt1 = ((t + 1) < NT ? (t + 1) : (NT - 1)) * 64;
    const int kt2 = ((t + 2) < NT ? (t + 2) : (NT - 1)) * 64;
    // ---- phase 0
    #pragma unroll
    for (int i = 0; i < 4; ++i) av[i] = *(const s8bf*)(ldsb + bo + aoff[i]);
    #pragma unroll
    for (int nf = 0; nf < 3; ++nf) bk[nf] = *(const s8bf*)(ldsb + bo + boff[nf]);
    gl_lds16(sA_lo + kt1 + 32, ldsb + bo2 + 16384 + d16);
    gl_lds16(sA_hi + kt1 + 32, ldsb + bo2 + 24576 + d16);
    __builtin_amdgcn_s_barrier();
    asm volatile("s_waitcnt lgkmcnt(0)" ::: "memory");
    __builtin_amdgcn_s_setprio(1);
    #pragma unroll
    for (int i = 0; i < 4; ++i)
      #pragma unroll
      for (int nf = 0; nf < 3; ++nf)
        acc[i][nf] = mfma16(av[i], bk[nf], acc[i][nf]);
    __builtin_amdgcn_s_setprio(0);
    __builtin_amdgcn_s_barrier();
    // ---- phase 1
    #pragma unroll
    for (int i = 0; i < 4; ++i) av2[i] = *(const s8bf*)(ldsb + bo + aoff[4 + i]);
    gl_lds16(sB_lo + kt1 + 32, ldsb + bo2 + 45056 + d16);
    if (wid < 4) gl_lds16(sB_hi + kt1 + 32, ldsb + bo2 + 53248 + d16);
    __builtin_amdgcn_s_barrier();
    asm volatile("s_waitcnt lgkmcnt(0)" ::: "memory");
    __builtin_amdgcn_s_setprio(1);
    #pragma unroll
    for (int i = 0; i < 4; ++i)
      #pragma unroll
      for (int nf = 0; nf < 3; ++nf)
        acc[4 + i][nf] = mfma16(av2[i], bk[nf], acc[4 + i][nf]);
    __builtin_amdgcn_s_setprio(0);
    if (wid < 4) asm volatile("s_waitcnt vmcnt(8)" ::: "memory");
    else         asm volatile("s_waitcnt vmcnt(6)" ::: "memory");
    __builtin_amdgcn_s_barrier();
    // ---- phase 2
    #pragma unroll
    for (int i = 0; i < 4; ++i) av[i] = *(const s8bf*)(ldsb + bo + 16384 + aoff[i]);
    #pragma unroll
    for (int nf = 0; nf < 3; ++nf) bk[nf] = *(const s8bf*)(ldsb + bo + 12288 + boff[nf]);
    gl_lds16(sA_lo + kt2, ldsb + bo + 0    + d16);
    gl_lds16(sA_hi + kt2, ldsb + bo + 8192 + d16);
    __builtin_amdgcn_s_barrier();
    asm volatile("s_waitcnt lgkmcnt(0)" ::: "memory");
    __builtin_amdgcn_s_setprio(1);
    #pragma unroll
    for (int i = 0; i < 4; ++i)
      #pragma unroll
      for (int nf = 0; nf < 3; ++nf)
        acc[i][nf] = mfma16(av[i], bk[nf], acc[i][nf]);
    __builtin_amdgcn_s_setprio(0);
    __builtin_amdgcn_s_barrier();
    // ---- phase 3
    #pragma unroll
    for (int i = 0; i < 4; ++i) av2[i] = *(const s8bf*)(ldsb + bo + 16384 + aoff[4 + i]);
    gl_lds16(sB_lo + kt2, ldsb + bo + 32768 + d16);
    if (wid < 4) gl_lds16(sB_hi + kt2, ldsb + bo + 40960 + d16);
    __builtin_amdgcn_s_barrier();
    asm volatile("s_waitcnt lgkmcnt(0)" ::: "memory");
    __builtin_amdgcn_s_setprio(1);
    #pragma unroll
    for (int i = 0; i < 4; ++i)
      #pragma unroll
      for (int nf = 0; nf < 3; ++nf)
        acc[4 + i][nf] = mfma16(av2[i], bk[nf], acc[4 + i][nf]);
    __builtin_amdgcn_s_setprio(0);
    if (wid < 4) asm volatile("s_waitcnt vmcnt(8)" ::: "memory");
    else         asm volatile("s_waitcnt vmcnt(6)" ::: "memory");
    __builtin_amdgcn_s_barrier();
  }
  asm volatile("s_waitcnt vmcnt(0)" ::: "memory");

  const int r0 = m0 + wm * 128 + ((lane >> 4) << 2);
  const int c0 = n0 + wn * 48 + (lane & 15);
  #pragma unroll
  for (int mf = 0; mf < 8; ++mf)
    #pragma unroll
    for (int nf = 0; nf < 3; ++nf)
      #pragma unroll
      for (int v = 0; v < 4; ++v) {
        int row = r0 + mf * 16 + v, col = c0 + nf * 16;
        float val = acc[mf][nf][v];
        if (MODE == 0) ((short*)C)[(size_t)row * N + col] = f2bf(val);
        else           ((float*)C)[(size_t)row * N + col] = val;
      }
}

// ---------------- m97-style GEMM for split-K K/V projection ----------------
// MODE 5: per-slice f32 partial store (no atomics): C[z][row][col], slice stride 256*3072
template<int MODE>
__global__ __launch_bounds__(256, 2) void gemm_bt_k(
    const short* __restrict__ A, const short* __restrict__ Bt, void* __restrict__ C,
    int M, int N, int K, int kchunk)
{
  __shared__ short aT[128 * 32];
  __shared__ short bT[128 * 32];
  const int m0 = blockIdx.x * 128, n0 = blockIdx.y * 128;
  const int wid = threadIdx.x >> 6, lane = threadIdx.x & 63;
  const int wr = wid >> 1, wc = wid & 1;
  const int k_lo = blockIdx.z * kchunk, k_hi = k_lo + kchunk;
  f32x4 acc[4][4] = {};
  const int srow = wid * 32 + (lane >> 2);
  const int skoff = (lane & 3) * 8;
  const short* aG = A + (size_t)(m0 + srow) * K + skoff;
  const short* bG = Bt + (size_t)(n0 + srow) * K + skoff;
  char* aL = (char*)aT + wid * 2048;
  char* bL = (char*)bT + wid * 2048;
  const short* ap = aT + (wr * 64 + (lane & 15)) * 32 + (lane >> 4) * 8;
  const short* bp = bT + (wc * 64 + (lane & 15)) * 32 + (lane >> 4) * 8;
  for (int k0 = k_lo; k0 < k_hi; k0 += 32) {
    gl_lds16(aG + k0, aL);
    gl_lds16(aG + (size_t)16 * K + k0, aL + 1024);
    gl_lds16(bG + k0, bL);
    gl_lds16(bG + (size_t)16 * K + k0, bL + 1024);
    __syncthreads();
    s8bf af[4], bf[4];
    #pragma unroll
    for (int i = 0; i < 4; ++i) {
      af[i] = *(const s8bf*)(ap + i * 512);
      bf[i] = *(const s8bf*)(bp + i * 512);
    }
    #pragma unroll
    for (int mi = 0; mi < 4; ++mi)
      #pragma unroll
      for (int ni = 0; ni < 4; ++ni)
        acc[mi][ni] = mfma16(af[mi], bf[ni], acc[mi][ni]);
    __syncthreads();
  }
  const int r0 = m0 + wr * 64 + ((lane >> 4) << 2);
  const int c0 = n0 + wc * 64 + (lane & 15);
  float* Cf = (float*)C + (size_t)blockIdx.z * 786432;
  #pragma unroll
  for (int mi = 0; mi < 4; ++mi)
    #pragma unroll
    for (int ni = 0; ni < 4; ++ni)
      #pragma unroll
      for (int v = 0; v < 4; ++v) {
        int row = r0 + mi * 16 + v, col = c0 + ni * 16;
        Cf[(size_t)row * N + col] = acc[mi][ni][v];
      }
}

// ---------------- reduce 4 split-K slices -> bf16 K (row-major) + V^T ----------------
__global__ void kv_reduce_k(const float* __restrict__ part, short* __restrict__ kbf,
                            short* __restrict__ vtbf) {
  int t = blockIdx.x * 256 + threadIdx.x;          // t < 196608
  int row = t / 768, c4 = (t % 768) * 4;
  float4 s = {0.f, 0.f, 0.f, 0.f};
  const float* p = part + (size_t)row * 3072 + c4;
  #pragma unroll
  for (int z = 0; z < 4; ++z) {
    float4 v = *(const float4*)(p + (size_t)z * 786432);
    s.x += v.x; s.y += v.y; s.z += v.z; s.w += v.w;
  }
  if (c4 < 1536) {
    short4 o = { f2bf(s.x), f2bf(s.y), f2bf(s.z), f2bf(s.w) };
    *(short4*)(kbf + (size_t)row * 1536 + c4) = o;
  } else {
    int b = row >> 7, j = row & 127, c = c4 - 1536;
    vtbf[((size_t)(b * 1536 + c + 0)) * 128 + j] = f2bf(s.x);
    vtbf[((size_t)(b * 1536 + c + 1)) * 128 + j] = f2bf(s.y);
    vtbf[((size_t)(b * 1536 + c + 2)) * 128 + j] = f2bf(s.z);
    vtbf[((size_t)(b * 1536 + c + 3)) * 128 + j] = f2bf(s.w);
  }
}

// ---------------- fused attention for one (i-tile=128, head, batch) ----------------
// LDS 48KB: kT [0,16K), vT [16K,32K), P: waves 0/1 alias dead kT, waves 2/3 at [32K,48K)
__global__ __launch_bounds__(256, 3) void attn_k(
    const short* __restrict__ q, const short* __restrict__ kk,
    const short* __restrict__ vt, const float* __restrict__ bias,
    short* __restrict__ ao)
{
  __shared__ char sm_[49152];
  const int it = blockIdx.x, h = blockIdx.y, b = blockIdx.z;
  const int wid = threadIdx.x >> 6, lane = threadIdx.x & 63;
  const int i0 = it * 128;
  char* kT = sm_;
  char* vT = sm_ + 16384;
  char* pB = (wid < 2) ? (sm_ + wid * 8192) : (sm_ + 16384 + wid * 8192);

  #pragma unroll
  for (int c = 0; c < 4; ++c) {
    int seg = c * 256 + wid * 64 + lane;
    int j = seg >> 3, ds = seg & 7;
    int dsrc = ds ^ (j & 7);
    gl_lds16(kk + ((size_t)(b * 128 + j) * 1536 + h * 64 + dsrc * 8),
             kT + c * 4096 + wid * 1024);
  }
  #pragma unroll
  for (int c = 0; c < 4; ++c) {
    int seg = c * 256 + wid * 64 + lane;
    int d = seg >> 4, js = seg & 15;
    int jsrc = js ^ (d & 7);
    gl_lds16(vt + ((size_t)(b * 1536 + h * 64 + d) * 128 + jsrc * 8),
             vT + c * 4096 + wid * 1024);
  }

  float bcol[8];
  #pragma unroll
  for (int nj = 0; nj < 8; ++nj) bcol[nj] = bias[b * 128 + nj * 16 + (lane & 15)];

  s8bf qf[2][2];
  #pragma unroll
  for (int mi = 0; mi < 2; ++mi)
    #pragma unroll
    for (int ks = 0; ks < 2; ++ks) {
      size_t row = (size_t)(b * 4096 + i0 + wid * 32 + mi * 16 + (lane & 15));
      qf[mi][ks] = *(const s8bf*)(q + row * 1536 + h * 64 + ks * 32 + (lane >> 4) * 8);
    }
  __syncthreads();

  f32x4 s[2][8] = {};
  #pragma unroll
  for (int ks = 0; ks < 2; ++ks) {
    int kd = ks * 32 + (lane >> 4) * 8;
    #pragma unroll
    for (int nj = 0; nj < 8; ++nj) {
      int j = nj * 16 + (lane & 15);
      s8bf kb = *(const s8bf*)(kT + j * 128 + ((2 * kd) ^ ((j & 7) << 4)));
      s[0][nj] = mfma16(qf[0][ks], kb, s[0][nj]);
      s[1][nj] = mfma16(qf[1][ks], kb, s[1][nj]);
    }
  }
  __syncthreads();   // kT handoff: all waves done with K before P overlays it

  float sm[2][4];
  #pragma unroll
  for (int mi = 0; mi < 2; ++mi)
    #pragma unroll
    for (int v = 0; v < 4; ++v) {
      float mx = -1e30f;
      #pragma unroll
      for (int nj = 0; nj < 8; ++nj) {
        float sv = s[mi][nj][v] * 0.125f + bcol[nj];
        s[mi][nj][v] = sv;
        mx = fmaxf(mx, sv);
      }
      mx = fmaxf(mx, __shfl_xor(mx, 1));
      mx = fmaxf(mx, __shfl_xor(mx, 2));
      mx = fmaxf(mx, __shfl_xor(mx, 4));
      mx = fmaxf(mx, __shfl_xor(mx, 8));
      float ss = 0.f;
      #pragma unroll
      for (int nj = 0; nj < 8; ++nj) {
        float p = __expf(s[mi][nj][v] - mx);
        s[mi][nj][v] = p;
        ss += p;
      }
      ss += __shfl_xor(ss, 1);
      ss += __shfl_xor(ss, 2);
      ss += __shfl_xor(ss, 4);
      ss += __shfl_xor(ss, 8);
      sm[mi][v] = ss;
    }

  #pragma unroll
  for (int mi = 0; mi < 2; ++mi)
    #pragma unroll
    for (int v = 0; v < 4; ++v) {
      int r = mi * 16 + ((lane >> 4) << 2) + v;
      char* base = pB + r * 256;
      #pragma unroll
      for (int nj = 0; nj < 8; ++nj) {
        int j = nj * 16 + (lane & 15);
        *(short*)(base + ((2 * j) ^ ((r & 7) << 4))) = f2bf(s[mi][nj][v]);
      }
    }
  __syncthreads();

  f32x4 o_[2][4] = {};
  #pragma unroll
  for (int ks = 0; ks < 4; ++ks) {
    int j = ks * 32 + (lane >> 4) * 8;
    s8bf pa[2];
    #pragma unroll
    for (int mi = 0; mi < 2; ++mi) {
      int r = mi * 16 + (lane & 15);
      pa[mi] = *(const s8bf*)(pB + r * 256 + ((2 * j) ^ ((r & 7) << 4)));
    }
    #pragma unroll
    for (int dj = 0; dj < 4; ++dj) {
      int d = dj * 16 + (lane & 15);
      s8bf vb = *(const s8bf*)(vT + d * 256 + ((2 * j) ^ ((d & 7) << 4)));
      o_[0][dj] = mfma16(pa[0], vb, o_[0][dj]);
      o_[1][dj] = mfma16(pa[1], vb, o_[1][dj]);
    }
  }

  #pragma unroll
  for (int mi = 0; mi < 2; ++mi)
    #pragma unroll
    for (int v = 0; v < 4; ++v) {
      int r = mi * 16 + ((lane >> 4) << 2) + v;
      float is = 1.0f / sm[mi][v];
      size_t row = (size_t)(b * 4096 + i0 + wid * 32 + r);
      #pragma unroll
      for (int dj = 0; dj < 4; ++dj) {
        int d = dj * 16 + (lane & 15);
        ao[row * 1536 + h * 64 + d] = f2bf(o_[mi][dj][v] * is);
      }
    }
}

extern "C" void kernel_launch(void* const* d_in, const int* in_sizes, int n_in,
                              void* d_out, int out_size, void* d_ws, size_t ws_size,
                              hipStream_t stream) {
  const float* x   = (const float*)d_in[0];
  const float* ctx = (const float*)d_in[1];
  const void*  msk = d_in[2];
  const float* Wq  = (const float*)d_in[3];
  const float* Wk  = (const float*)d_in[4];
  const float* Wv  = (const float*)d_in[5];
  const float* Wo  = (const float*)d_in[6];
  float* out = (float*)d_out;

  const int B = 2, NI = 4096, NT = 128, C = 1536, CC = 4096, H = 24;
  const int Mq = B * NI;  // 8192
  const int Mk = B * NT;  // 256

  size_t off = 0;
  auto carve = [&](size_t bytes) -> void* {
    void* p = (char*)d_ws + off;
    off += (bytes + 255) & ~(size_t)255;
    return p;
  };
  short* xbf   = (short*)carve((size_t)Mq * C * 2);   // reused as attn-out after Q-proj
  short* ctxbf = (short*)carve((size_t)Mk * CC * 2);
  short* WqT   = (short*)carve((size_t)C * C * 2);
  short* WkT   = (short*)carve((size_t)CC * C * 2);   // WvT must follow contiguously
  short* WvT   = (short*)carve((size_t)CC * C * 2);
  short* WoT   = (short*)carve((size_t)C * C * 2);
  short* qbf   = (short*)carve((size_t)Mq * C * 2);
  short* kbf   = (short*)carve((size_t)Mk * C * 2);
  short* vtbf  = (short*)carve((size_t)Mk * C * 2);
  float* bias  = (float*)carve(256 * 4);
  short* aout  = xbf;            // alias: x dead after Q-proj
  float* part  = out;            // d_out as split-K scratch (12.6MB, fully overwritten later)

  // allow 112KB dynamic LDS on the pipelined GEMMs (idempotent, capture-safe)
  hipFuncSetAttribute((const void*)gemm4ph_k<0>, hipFuncAttributeMaxDynamicSharedMemorySize, 114688);
  hipFuncSetAttribute((const void*)gemm4ph_k<1>, hipFuncAttributeMaxDynamicSharedMemorySize, 114688);

  // fused pre-pass v2 (ILP casts + 64x64 transposes + mask) in one launch
  prep_k<<<7553, 256, 0, stream>>>(x, ctx, msk, Wq, Wk, Wv, Wo,
                                   xbf, ctxbf, WqT, WkT, WvT, WoT, bias);

  // Q projection (4-phase GEMM, bf16 out): grid 32x8 = 256 (full CU coverage)
  gemm4ph_k<0><<<(Mq / 256) * (C / 192), 512, 114688, stream>>>(xbf, WqT, qbf, Mq, C, C);
  // K+V projections merged: split-K=4 f32 partials into d_out scratch, then reduce
  gemm_bt_k<5><<<dim3(Mk / 128, 3072 / 128, 4), 256, 0, stream>>>(ctxbf, WkT, part, Mk, 3072, CC, 1024);
  kv_reduce_k<<<768, 256, 0, stream>>>(part, kbf, vtbf);

  // fused attention
  attn_k<<<dim3(NI / 128, H, B), 256, 0, stream>>>(qbf, kbf, vtbf, bias, aout);

  // output projection (4-phase GEMM, f32 out)
  gemm4ph_k<1><<<(Mq / 256) * (C / 192), 512, 114688, stream>>>(aout, WoT, out, Mq, C, C);
}